// Round 1
// baseline (6802.979 us; speedup 1.0000x reference)
//
#include <hip/hip_runtime.h>
#include <hip/hip_bf16.h>
#include <math.h>

// Problem constants
#define D_EMB  1024
#define T_TOK  1024
#define T1_TOK 768
#define T2_TOK 256
#define NBATCH 4
#define HMLP   4096
#define NLAYER 12
#define VCLS   512

typedef __attribute__((ext_vector_type(8))) short  short8;   // 8 bf16 (4 VGPRs)
typedef __attribute__((ext_vector_type(4))) float  f32x4;

__device__ __forceinline__ unsigned short f2bf(float f) {
    union { float f; unsigned int u; } c; c.f = f;
    unsigned int u = c.u;
    return (unsigned short)((u + 0x7FFFu + ((u >> 16) & 1u)) >> 16); // RNE
}

__device__ __forceinline__ void cvt16(unsigned short* dst, float4 a0, float4 a1,
                                      float4 a2, float4 a3) {
    union { unsigned short s[16]; short8 v[2]; } t;
    t.s[0]=f2bf(a0.x);  t.s[1]=f2bf(a0.y);  t.s[2]=f2bf(a0.z);  t.s[3]=f2bf(a0.w);
    t.s[4]=f2bf(a1.x);  t.s[5]=f2bf(a1.y);  t.s[6]=f2bf(a1.z);  t.s[7]=f2bf(a1.w);
    t.s[8]=f2bf(a2.x);  t.s[9]=f2bf(a2.y);  t.s[10]=f2bf(a2.z); t.s[11]=f2bf(a2.w);
    t.s[12]=f2bf(a3.x); t.s[13]=f2bf(a3.y); t.s[14]=f2bf(a3.z); t.s[15]=f2bf(a3.w);
    *(short8*)dst       = t.v[0];
    *((short8*)dst + 1) = t.v[1];
}

// ---------------------------------------------------------------------------
// Embedding: H[b,t,:] = (t<T2 ? i_emb[zi[b,t]] : t_emb[xt[b,t-T2]]) + pos[t]
// ---------------------------------------------------------------------------
__global__ __launch_bounds__(256)
void embed_kernel(const int* __restrict__ xt, const int* __restrict__ zi,
                  const float* __restrict__ pos, const float* __restrict__ temb,
                  const float* __restrict__ iemb, float* __restrict__ H)
{
    const long idx = (long)blockIdx.x * 256 + threadIdx.x; // one float4 each
    const long e   = idx * 4;
    const int  dd  = (int)(e & (D_EMB - 1));
    const long bt  = e >> 10;
    const int  t   = (int)(bt & (T_TOK - 1));
    const int  b   = (int)(bt >> 10);
    const float* src;
    if (t < T2_TOK) src = iemb + (long)zi[b * T2_TOK + t] * D_EMB + dd;
    else            src = temb + (long)xt[b * T1_TOK + (t - T2_TOK)] * D_EMB + dd;
    float4 sv = *(const float4*)src;
    float4 pv = *(const float4*)(pos + (long)t * D_EMB + dd);
    float4 o; o.x = sv.x + pv.x; o.y = sv.y + pv.y; o.z = sv.z + pv.z; o.w = sv.w + pv.w;
    *(float4*)(H + e) = o;
}

// ---------------------------------------------------------------------------
// LayerNorm: one block per row of 1024
// ---------------------------------------------------------------------------
__global__ __launch_bounds__(256)
void ln_kernel(const float* __restrict__ X, const float* __restrict__ g,
               const float* __restrict__ b, float* __restrict__ Y)
{
    const long row = blockIdx.x;
    const int  tid = threadIdx.x;
    float4 v = *(const float4*)(X + row * D_EMB + tid * 4);
    float s = v.x + v.y + v.z + v.w;
    float q = v.x*v.x + v.y*v.y + v.z*v.z + v.w*v.w;
    #pragma unroll
    for (int o = 32; o >= 1; o >>= 1) { s += __shfl_down(s, o); q += __shfl_down(q, o); }
    __shared__ float rs[4], rq[4];
    const int w = tid >> 6;
    if ((tid & 63) == 0) { rs[w] = s; rq[w] = q; }
    __syncthreads();
    s = rs[0] + rs[1] + rs[2] + rs[3];
    q = rq[0] + rq[1] + rq[2] + rq[3];
    const float mean = s * (1.0f / D_EMB);
    const float var  = q * (1.0f / D_EMB) - mean * mean;
    const float rstd = rsqrtf(var + 1e-5f);
    float4 gg = *(const float4*)(g + tid * 4);
    float4 bb = *(const float4*)(b + tid * 4);
    float4 o;
    o.x = (v.x - mean) * rstd * gg.x + bb.x;
    o.y = (v.y - mean) * rstd * gg.y + bb.y;
    o.z = (v.z - mean) * rstd * gg.z + bb.z;
    o.w = (v.w - mean) * rstd * gg.w + bb.w;
    *(float4*)(Y + row * D_EMB + tid * 4) = o;
}

// ---------------------------------------------------------------------------
// Row softmax over 1024 with logit scale 1/32, in-place fp32
// ---------------------------------------------------------------------------
__global__ __launch_bounds__(256)
void softmax_kernel(float* __restrict__ P)
{
    const long row = blockIdx.x;
    const int  tid = threadIdx.x;
    float* p = P + row * T_TOK + tid * 4;
    float4 v = *(const float4*)p;
    const float sc = 0.03125f; // 1/sqrt(1024)
    float a = v.x * sc, b = v.y * sc, c = v.z * sc, d = v.w * sc;
    float mx = fmaxf(fmaxf(a, b), fmaxf(c, d));
    #pragma unroll
    for (int o = 32; o >= 1; o >>= 1) mx = fmaxf(mx, __shfl_down(mx, o));
    __shared__ float rm[4], rsum[4];
    const int w = tid >> 6;
    if ((tid & 63) == 0) rm[w] = mx;
    __syncthreads();
    mx = fmaxf(fmaxf(rm[0], rm[1]), fmaxf(rm[2], rm[3]));
    float e0 = expf(a - mx), e1 = expf(b - mx), e2 = expf(c - mx), e3 = expf(d - mx);
    float s = e0 + e1 + e2 + e3;
    #pragma unroll
    for (int o = 32; o >= 1; o >>= 1) s += __shfl_down(s, o);
    if ((tid & 63) == 0) rsum[w] = s;
    __syncthreads();
    s = rsum[0] + rsum[1] + rsum[2] + rsum[3];
    const float inv = 1.0f / s;
    float4 o4; o4.x = e0 * inv; o4.y = e1 * inv; o4.z = e2 * inv; o4.w = e3 * inv;
    *(float4*)p = o4;
}

// ---------------------------------------------------------------------------
// Generic bf16-MFMA GEMM: C = epilogue(A @ B), fp32 in/out, bf16 convert in
// staging. 128x128 tile, BK=32, 4 waves (2x2), per-wave 64x64 via 4x4 frags
// of v_mfma_f32_16x16x32_bf16.
// BTRANS=true : B is row-major [K][N]  (NN; transpose-scatter into LDS)
// BTRANS=false: B is row-major [N][K]  (NT; straight copy, used for Q@K^T)
// EPI: 0 store, 1 bias+gelu(erf), 2 C+=acc+bias, 3 C+=alpha*acc, 4 readout
// ---------------------------------------------------------------------------
template<int EPI, bool BTRANS>
__global__ __launch_bounds__(256)
void gemm_kernel(const float* __restrict__ A, const float* __restrict__ B0,
                 const float* __restrict__ B1, const float* __restrict__ B2,
                 float* __restrict__ C, const float* __restrict__ bias,
                 int M, int N, int K,
                 long sAz, long sBz, long sCz, float alpha)
{
    __shared__ unsigned short As[128][40]; // [m][k], +8 pad: 2-way banks only
    __shared__ unsigned short Bs[128][40]; // [n][k]

    const int z = blockIdx.z;
    const float* Bp = (B1 != nullptr) ? (z == 0 ? B0 : (z == 1 ? B1 : B2))
                                      : (B0 + (long)z * sBz);
    const float* Ap = A + (long)z * sAz;
    const long czoff = (long)z * sCz;

    const int tid = threadIdx.x;
    const int m0 = blockIdx.y * 128;
    const int n0 = blockIdx.x * 128;

    const int l  = tid & 63;
    const int w  = tid >> 6;
    const int wm = (w >> 1) * 64;
    const int wn = (w & 1) * 64;
    const int lr = l & 15;         // A row / B col / D col within fragment
    const int lk = (l >> 4) * 8;   // k offset within fragment

    f32x4 acc[4][4];
    #pragma unroll
    for (int f = 0; f < 4; ++f)
        #pragma unroll
        for (int gq = 0; gq < 4; ++gq)
            acc[f][gq] = (f32x4){0.f, 0.f, 0.f, 0.f};

    const int sar = tid >> 1;        // 0..127 tile row (A / NT-B)
    const int sak = (tid & 1) * 16;  // k half
    const int sbk = tid >> 3;        // 0..31  (NN-B k row)
    const int sbn = (tid & 7) * 16;  // n chunk

    const int nkt = K >> 5;
    for (int t = 0; t < nkt; ++t) {
        const int k0 = t << 5;
        {
            const float* srcA = Ap + (long)(m0 + sar) * K + (k0 + sak);
            float4 a0 = *(const float4*)(srcA + 0);
            float4 a1 = *(const float4*)(srcA + 4);
            float4 a2 = *(const float4*)(srcA + 8);
            float4 a3 = *(const float4*)(srcA + 12);
            cvt16(&As[sar][sak], a0, a1, a2, a3);
        }
        if constexpr (BTRANS) {
            const float* srcB = Bp + (long)(k0 + sbk) * N + (n0 + sbn);
            float4 b0v = *(const float4*)(srcB + 0);
            float4 b1v = *(const float4*)(srcB + 4);
            float4 b2v = *(const float4*)(srcB + 8);
            float4 b3v = *(const float4*)(srcB + 12);
            float vals[16] = {b0v.x, b0v.y, b0v.z, b0v.w, b1v.x, b1v.y, b1v.z, b1v.w,
                              b2v.x, b2v.y, b2v.z, b2v.w, b3v.x, b3v.y, b3v.z, b3v.w};
            #pragma unroll
            for (int i = 0; i < 16; ++i) Bs[sbn + i][sbk] = f2bf(vals[i]);
        } else {
            const float* srcB = Bp + (long)(n0 + sar) * K + (k0 + sak);
            float4 b0v = *(const float4*)(srcB + 0);
            float4 b1v = *(const float4*)(srcB + 4);
            float4 b2v = *(const float4*)(srcB + 8);
            float4 b3v = *(const float4*)(srcB + 12);
            cvt16(&Bs[sar][sak], b0v, b1v, b2v, b3v);
        }
        __syncthreads();
        short8 af[4], bg[4];
        #pragma unroll
        for (int f = 0; f < 4; ++f)
            af[f] = *(const short8*)&As[wm + f * 16 + lr][lk];
        #pragma unroll
        for (int gq = 0; gq < 4; ++gq)
            bg[gq] = *(const short8*)&Bs[wn + gq * 16 + lr][lk];
        #pragma unroll
        for (int f = 0; f < 4; ++f)
            #pragma unroll
            for (int gq = 0; gq < 4; ++gq)
                acc[f][gq] = __builtin_amdgcn_mfma_f32_16x16x32_bf16(
                    af[f], bg[gq], acc[f][gq], 0, 0, 0);
        __syncthreads();
    }

    // Epilogue. D mapping: col = lane&15, row = (lane>>4)*4 + r   [m89]
    #pragma unroll
    for (int f = 0; f < 4; ++f) {
        #pragma unroll
        for (int gq = 0; gq < 4; ++gq) {
            #pragma unroll
            for (int r = 0; r < 4; ++r) {
                const int gm = m0 + wm + f * 16 + (l >> 4) * 4 + r;
                const int gn = n0 + wn + gq * 16 + lr;
                float v = acc[f][gq][r];
                if (EPI == 0) {
                    C[czoff + (long)gm * N + gn] = v;
                } else if (EPI == 1) {
                    v += bias[gn];
                    C[(long)gm * N + gn] = 0.5f * v * (1.0f + erff(v * 0.70710678118f));
                } else if (EPI == 2) {
                    const long o = (long)gm * N + gn;
                    C[o] = C[o] + v + bias[gn];
                } else if (EPI == 3) {
                    const long o = czoff + (long)gm * N + gn;
                    C[o] = C[o] + alpha * v;
                } else { // readout: rows with t>=T2 only, remapped
                    const int tt = gm & (T_TOK - 1);
                    if (tt >= T2_TOK) {
                        const int bb = gm >> 10;
                        C[(long)(bb * T1_TOK + (tt - T2_TOK)) * VCLS + gn] = v + bias[gn];
                    }
                }
            }
        }
    }
}

// ---------------------------------------------------------------------------
extern "C" void kernel_launch(void* const* d_in, const int* in_sizes, int n_in,
                              void* d_out, int out_size, void* d_ws, size_t ws_size,
                              hipStream_t stream)
{
    (void)in_sizes; (void)n_in; (void)out_size; (void)ws_size;
    const int*   xt   = (const int*)d_in[0];
    const int*   zi   = (const int*)d_in[1];
    const float* pos  = (const float*)d_in[2];
    const float* temb = (const float*)d_in[3];
    const float* iemb = (const float*)d_in[4];
    const float* ln1g = (const float*)d_in[5];
    const float* ln1b = (const float*)d_in[6];
    const float* Wq   = (const float*)d_in[7];
    const float* Wk   = (const float*)d_in[8];
    const float* Wv   = (const float*)d_in[9];
    const float* ln2g = (const float*)d_in[10];
    const float* ln2b = (const float*)d_in[11];
    const float* W1   = (const float*)d_in[12];
    const float* b1   = (const float*)d_in[13];
    const float* W2   = (const float*)d_in[14];
    const float* b2   = (const float*)d_in[15];
    const float* roW  = (const float*)d_in[16];
    const float* rob  = (const float*)d_in[17];
    float* out = (float*)d_out;

    // Workspace (fp32): H | LN | Q K V P (MLP hidden overlaps Q..P)
    float* ws  = (float*)d_ws;
    float* H   = ws;                 // 4096x1024
    float* LNb = ws + 4194304;       // 4096x1024
    float* Qb  = ws + 8388608;       // 4096x1024
    float* Kb  = ws + 12582912;
    float* Vb  = ws + 16777216;
    float* Pb  = ws + 20971520;      // 4x1024x1024
    float* Hid = ws + 8388608;       // 4096x4096 (overlaps Q,K,V,P)
    // total: 25165824 floats = 100.7 MB

    const long TD = (long)T_TOK * D_EMB;
    const long TT = (long)T_TOK * T_TOK;

    embed_kernel<<<4096, 256, 0, stream>>>(xt, zi, pos, temb, iemb, H);

    for (int lyr = 0; lyr < NLAYER; ++lyr) {
        const long dd  = (long)lyr * D_EMB * D_EMB;
        const long d1  = (long)lyr * D_EMB * HMLP;
        ln_kernel<<<4096, 256, 0, stream>>>(H, ln1g + lyr * D_EMB, ln1b + lyr * D_EMB, LNb);
        // Q,K,V via grid.z
        gemm_kernel<0, true><<<dim3(8, 32, 3), 256, 0, stream>>>(
            LNb, Wq + dd, Wk + dd, Wv + dd, Qb, nullptr,
            4096, D_EMB, D_EMB, 0L, 0L, (long)4194304, 1.f);
        // scores = Q @ K^T per batch (NT)
        gemm_kernel<0, false><<<dim3(8, 8, 4), 256, 0, stream>>>(
            Qb, Kb, nullptr, nullptr, Pb, nullptr,
            T_TOK, T_TOK, D_EMB, TD, TD, TT, 1.f);
        softmax_kernel<<<4096, 256, 0, stream>>>(Pb);
        // H += (1+1/D) * P @ V per batch
        gemm_kernel<3, true><<<dim3(8, 8, 4), 256, 0, stream>>>(
            Pb, Vb, nullptr, nullptr, H, nullptr,
            T_TOK, D_EMB, T_TOK, TT, TD, TD, 1.0f + 1.0f / (float)D_EMB);
        ln_kernel<<<4096, 256, 0, stream>>>(H, ln2g + lyr * D_EMB, ln2b + lyr * D_EMB, LNb);
        // hidden = gelu(LN @ W1 + b1)
        gemm_kernel<1, true><<<dim3(32, 32, 1), 256, 0, stream>>>(
            LNb, W1 + d1, nullptr, nullptr, Hid, b1 + (long)lyr * HMLP,
            4096, HMLP, D_EMB, 0L, 0L, 0L, 1.f);
        // H += hidden @ W2 + b2
        gemm_kernel<2, true><<<dim3(8, 32, 1), 256, 0, stream>>>(
            Hid, W2 + d1, nullptr, nullptr, H, b2 + (long)lyr * D_EMB,
            4096, D_EMB, HMLP, 0L, 0L, 0L, 1.f);
    }
    // readout: out = (H @ ro_W + ro_b)[:, T2:, :]
    gemm_kernel<4, true><<<dim3(4, 32, 1), 256, 0, stream>>>(
        H, roW, nullptr, nullptr, out, rob,
        4096, VCLS, D_EMB, 0L, 0L, 0L, 1.f);
}

// Round 2
// 3690.925 us; speedup vs baseline: 1.8432x; 1.8432x over previous
//
#include <hip/hip_runtime.h>
#include <hip/hip_bf16.h>
#include <math.h>

#define D_EMB  1024
#define T_TOK  1024
#define T1_TOK 768
#define T2_TOK 256
#define HMLP   4096
#define NLAYER 12
#define VCLS   512

typedef __attribute__((ext_vector_type(8))) short          short8; // 8 bf16
typedef __attribute__((ext_vector_type(4))) float          f32x4;
typedef __attribute__((ext_vector_type(4))) unsigned short us4;

__device__ __forceinline__ unsigned short f2bf(float f) {
    union { float f; unsigned int u; } c; c.f = f;
    unsigned int u = c.u;
    return (unsigned short)((u + 0x7FFFu + ((u >> 16) & 1u)) >> 16); // RNE
}

// async global->LDS, 16B per lane. LDS dest must be wave-uniform base (HW
// adds lane*16). Global src is per-lane.
__device__ __forceinline__ void gld_lds16(const unsigned short* g, unsigned short* l) {
    __builtin_amdgcn_global_load_lds(
        (__attribute__((address_space(1))) void*)g,
        (__attribute__((address_space(3))) void*)l, 16, 0, 0);
}

// ---------------------------------------------------------------------------
// Embedding: H[b,t,:] = (t<T2 ? i_emb[zi] : t_emb[xt]) + pos[t]   (fp32)
// ---------------------------------------------------------------------------
__global__ __launch_bounds__(256)
void embed_kernel(const int* __restrict__ xt, const int* __restrict__ zi,
                  const float* __restrict__ pos, const float* __restrict__ temb,
                  const float* __restrict__ iemb, float* __restrict__ H)
{
    const long idx = (long)blockIdx.x * 256 + threadIdx.x;
    const long e   = idx * 4;
    const int  dd  = (int)(e & (D_EMB - 1));
    const long bt  = e >> 10;
    const int  t   = (int)(bt & (T_TOK - 1));
    const int  b   = (int)(bt >> 10);
    const float* src;
    if (t < T2_TOK) src = iemb + (long)zi[b * T2_TOK + t] * D_EMB + dd;
    else            src = temb + (long)xt[b * T1_TOK + (t - T2_TOK)] * D_EMB + dd;
    float4 sv = *(const float4*)src;
    float4 pv = *(const float4*)(pos + (long)t * D_EMB + dd);
    float4 o; o.x = sv.x + pv.x; o.y = sv.y + pv.y; o.z = sv.z + pv.z; o.w = sv.w + pv.w;
    *(float4*)(H + e) = o;
}

// ---------------------------------------------------------------------------
// LayerNorm fp32 -> bf16, one block per row of 1024
// ---------------------------------------------------------------------------
__global__ __launch_bounds__(256)
void ln_kernel(const float* __restrict__ X, const float* __restrict__ g,
               const float* __restrict__ b, unsigned short* __restrict__ Y)
{
    const long row = blockIdx.x;
    const int  tid = threadIdx.x;
    float4 v = *(const float4*)(X + row * D_EMB + tid * 4);
    float s = v.x + v.y + v.z + v.w;
    float q = v.x*v.x + v.y*v.y + v.z*v.z + v.w*v.w;
    #pragma unroll
    for (int o = 32; o >= 1; o >>= 1) { s += __shfl_down(s, o); q += __shfl_down(q, o); }
    __shared__ float rs[4], rq[4];
    const int w = tid >> 6;
    if ((tid & 63) == 0) { rs[w] = s; rq[w] = q; }
    __syncthreads();
    s = rs[0] + rs[1] + rs[2] + rs[3];
    q = rq[0] + rq[1] + rq[2] + rq[3];
    const float mean = s * (1.0f / D_EMB);
    const float var  = q * (1.0f / D_EMB) - mean * mean;
    const float rstd = rsqrtf(var + 1e-5f);
    float4 gg = *(const float4*)(g + tid * 4);
    float4 bb = *(const float4*)(b + tid * 4);
    us4 o;
    o.x = f2bf((v.x - mean) * rstd * gg.x + bb.x);
    o.y = f2bf((v.y - mean) * rstd * gg.y + bb.y);
    o.z = f2bf((v.z - mean) * rstd * gg.z + bb.z);
    o.w = f2bf((v.w - mean) * rstd * gg.w + bb.w);
    *(us4*)(Y + row * D_EMB + tid * 4) = o;
}

// ---------------------------------------------------------------------------
// Row softmax over 1024 (scale 1/32): fp32 scores in, bf16 probs out
// ---------------------------------------------------------------------------
__global__ __launch_bounds__(256)
void softmax_kernel(const float* __restrict__ S, unsigned short* __restrict__ P)
{
    const long row = blockIdx.x;
    const int  tid = threadIdx.x;
    float4 v = *(const float4*)(S + row * T_TOK + tid * 4);
    const float sc = 0.03125f; // 1/sqrt(1024)
    float a = v.x * sc, b = v.y * sc, c = v.z * sc, d = v.w * sc;
    float mx = fmaxf(fmaxf(a, b), fmaxf(c, d));
    #pragma unroll
    for (int o = 32; o >= 1; o >>= 1) mx = fmaxf(mx, __shfl_down(mx, o));
    __shared__ float rm[4], rsum[4];
    const int w = tid >> 6;
    if ((tid & 63) == 0) rm[w] = mx;
    __syncthreads();
    mx = fmaxf(fmaxf(rm[0], rm[1]), fmaxf(rm[2], rm[3]));
    float e0 = expf(a - mx), e1 = expf(b - mx), e2 = expf(c - mx), e3 = expf(d - mx);
    float s = e0 + e1 + e2 + e3;
    #pragma unroll
    for (int o = 32; o >= 1; o >>= 1) s += __shfl_down(s, o);
    if ((tid & 63) == 0) rsum[w] = s;
    __syncthreads();
    s = rsum[0] + rsum[1] + rsum[2] + rsum[3];
    const float inv = 1.0f / s;
    us4 o4; o4.x = f2bf(e0 * inv); o4.y = f2bf(e1 * inv);
    o4.z = f2bf(e2 * inv); o4.w = f2bf(e3 * inv);
    *(us4*)(P + row * T_TOK + tid * 4) = o4;
}

// ---------------------------------------------------------------------------
// fp32 [K][N] -> bf16 [N][K] transpose-convert, 32x32 LDS tiles
// ---------------------------------------------------------------------------
__global__ __launch_bounds__(256)
void convT_kernel(const float* __restrict__ src, unsigned short* __restrict__ dst,
                  int K, int N)
{
    __shared__ unsigned short tile[32][33];
    const int tn = blockIdx.x, tk = blockIdx.y;
    const int tx = threadIdx.x & 31, ty = threadIdx.x >> 5;
    #pragma unroll
    for (int i = 0; i < 4; ++i) {
        const int r = ty + i * 8;
        tile[r][tx] = f2bf(src[(long)(tk * 32 + r) * N + tn * 32 + tx]);
    }
    __syncthreads();
    #pragma unroll
    for (int i = 0; i < 4; ++i) {
        const int r = ty + i * 8;
        dst[(long)(tn * 32 + r) * K + tk * 32 + tx] = tile[tx][r];
    }
}

// One layer's weights {Wq,Wk,Wv: [1024][1024], W1: [1024][4096], W2: [4096][1024]}
// -> bf16 transposed. grid.x = 3072 + 4096 + 4096 = 11264 tiles of 32x32.
__global__ __launch_bounds__(256)
void wconv_kernel(const float* __restrict__ Wq, const float* __restrict__ Wk,
                  const float* __restrict__ Wv, const float* __restrict__ W1,
                  const float* __restrict__ W2,
                  unsigned short* __restrict__ WqT, unsigned short* __restrict__ WkT,
                  unsigned short* __restrict__ WvT, unsigned short* __restrict__ W1T,
                  unsigned short* __restrict__ W2T)
{
    __shared__ unsigned short tile[32][33];
    const int t = blockIdx.x;
    const float* src; unsigned short* dst; int K, N, tk, tn;
    if (t < 3072) {
        const int wsel = t >> 10, tt = t & 1023;
        src = (wsel == 0) ? Wq : (wsel == 1) ? Wk : Wv;
        dst = (wsel == 0) ? WqT : (wsel == 1) ? WkT : WvT;
        K = 1024; N = 1024; tn = tt & 31; tk = tt >> 5;
    } else if (t < 7168) {
        const int tt = t - 3072;
        src = W1; dst = W1T; K = 1024; N = 4096; tn = tt & 127; tk = tt >> 7;
    } else {
        const int tt = t - 7168;
        src = W2; dst = W2T; K = 4096; N = 1024; tn = tt & 31; tk = tt >> 5;
    }
    const int tx = threadIdx.x & 31, ty = threadIdx.x >> 5;
    #pragma unroll
    for (int i = 0; i < 4; ++i) {
        const int r = ty + i * 8;
        tile[r][tx] = f2bf(src[(long)(tk * 32 + r) * N + tn * 32 + tx]);
    }
    __syncthreads();
    #pragma unroll
    for (int i = 0; i < 4; ++i) {
        const int r = ty + i * 8;
        dst[(long)(tn * 32 + r) * K + tk * 32 + tx] = tile[tx][r];
    }
}

// bf16 [T][D] -> bf16 [D][T] per batch (V transpose)
__global__ __launch_bounds__(256)
void vtrans_kernel(const unsigned short* __restrict__ src, unsigned short* __restrict__ dst)
{
    __shared__ unsigned short tile[32][33];
    const long so = (long)blockIdx.z * T_TOK * D_EMB;
    const int tn = blockIdx.x, tk = blockIdx.y;
    const int tx = threadIdx.x & 31, ty = threadIdx.x >> 5;
    #pragma unroll
    for (int i = 0; i < 4; ++i) {
        const int r = ty + i * 8;
        tile[r][tx] = src[so + (long)(tk * 32 + r) * D_EMB + tn * 32 + tx];
    }
    __syncthreads();
    #pragma unroll
    for (int i = 0; i < 4; ++i) {
        const int r = ty + i * 8;
        dst[so + (long)(tn * 32 + r) * T_TOK + tk * 32 + tx] = tile[tx][r];
    }
}

// fp32 -> bf16 elementwise (H -> Hbf before readout)
__global__ __launch_bounds__(256)
void cvt_bf16_kernel(const float* __restrict__ X, unsigned short* __restrict__ Y)
{
    const long i = ((long)blockIdx.x * 256 + threadIdx.x) * 4;
    float4 v = *(const float4*)(X + i);
    us4 o; o.x = f2bf(v.x); o.y = f2bf(v.y); o.z = f2bf(v.z); o.w = f2bf(v.w);
    *(us4*)(Y + i) = o;
}

// ---------------------------------------------------------------------------
// m97-structure bf16 GEMM: C = epi(A @ B^T). A [M][K] bf16, B [N][K] bf16.
// 128x128 tile, BK=32, 4 waves (2x2), 4x4 16x16x32 MFMA frags/wave.
// Staging: global_load_lds 16B/lane, linear LDS dest, k-slot XOR swizzle
// ((row>>1)&3) applied to BOTH global source and ds_read (rule #21) so
// fragment reads are bank-conflict-free.
// EPI: 0 fp32 store | 1 bias+gelu->bf16 | 2 C+=v+bias (fp32) |
//      3 C+=alpha*v (fp32) | 4 readout slice fp32 | 5 bf16 store
// ---------------------------------------------------------------------------
template<int EPI>
__global__ __launch_bounds__(256)
void gemm_bt(const unsigned short* __restrict__ A,
             const unsigned short* __restrict__ B0,
             const unsigned short* __restrict__ B1,
             const unsigned short* __restrict__ B2,
             void* __restrict__ C0, void* __restrict__ C1, void* __restrict__ C2,
             const float* __restrict__ bias,
             int M, int N, int K,
             long sAz, long sBz, long sCz, float alpha)
{
    __shared__ unsigned short As[128 * 32];
    __shared__ unsigned short Bs[128 * 32];

    const int z = blockIdx.z;
    const unsigned short* Ap = A + (long)z * sAz;
    const unsigned short* Bp = (B1 != nullptr) ? (z == 0 ? B0 : (z == 1 ? B1 : B2))
                                               : B0 + (long)z * sBz;
    void* Cp = (C1 != nullptr) ? (z == 0 ? C0 : (z == 1 ? C1 : C2)) : C0;
    const long czoff = (C1 != nullptr) ? 0 : (long)z * sCz;

    const int tid = threadIdx.x;
    const int l = tid & 63, w = tid >> 6;
    const int m0 = blockIdx.y * 128, n0 = blockIdx.x * 128;
    const int wm = (w >> 1) * 64, wn = (w & 1) * 64;
    const int lr = l & 15, hi = l >> 4;

    // staging geometry: i16 = j*256 + tid; row = i16>>2; slot = i16&3
    // global k-slot is (slot ^ ((row>>1)&3)) so linear LDS holds swizzled data
    const int r0 = tid >> 2;                    // rows 0..63 (j=0); +64 for j=1
    const int s0 = (tid & 3) ^ ((r0 >> 1) & 3); // same for j=1 (row+64 == row mod 8 shift)
    const unsigned short* gA0 = Ap + (long)(m0 + r0) * K + s0 * 8;
    const unsigned short* gA1 = Ap + (long)(m0 + r0 + 64) * K + s0 * 8;
    const unsigned short* gB0 = Bp + (long)(n0 + r0) * K + s0 * 8;
    const unsigned short* gB1 = Bp + (long)(n0 + r0 + 64) * K + s0 * 8;
    unsigned short* lA0 = As + (w * 64) * 8;        // wave-uniform bases
    unsigned short* lA1 = As + (256 + w * 64) * 8;
    unsigned short* lB0 = Bs + (w * 64) * 8;
    unsigned short* lB1 = Bs + (256 + w * 64) * 8;

    f32x4 acc[4][4];
    #pragma unroll
    for (int f = 0; f < 4; ++f)
        #pragma unroll
        for (int gq = 0; gq < 4; ++gq)
            acc[f][gq] = (f32x4){0.f, 0.f, 0.f, 0.f};

    for (int k0 = 0; k0 < K; k0 += 32) {
        gld_lds16(gA0 + k0, lA0);
        gld_lds16(gA1 + k0, lA1);
        gld_lds16(gB0 + k0, lB0);
        gld_lds16(gB1 + k0, lB1);
        __syncthreads();
        short8 af[4], bg[4];
        #pragma unroll
        for (int f = 0; f < 4; ++f) {
            const int rr = wm + f * 16 + lr;
            const int sl = hi ^ ((rr >> 1) & 3);
            af[f] = *(const short8*)&As[rr * 32 + sl * 8];
        }
        #pragma unroll
        for (int gq = 0; gq < 4; ++gq) {
            const int rn = wn + gq * 16 + lr;
            const int sl = hi ^ ((rn >> 1) & 3);
            bg[gq] = *(const short8*)&Bs[rn * 32 + sl * 8];
        }
        #pragma unroll
        for (int f = 0; f < 4; ++f)
            #pragma unroll
            for (int gq = 0; gq < 4; ++gq)
                acc[f][gq] = __builtin_amdgcn_mfma_f32_16x16x32_bf16(
                    af[f], bg[gq], acc[f][gq], 0, 0, 0);
        __syncthreads();
    }

    // D mapping: col = lane&15, row = (lane>>4)*4 + r
    #pragma unroll
    for (int f = 0; f < 4; ++f) {
        #pragma unroll
        for (int gq = 0; gq < 4; ++gq) {
            #pragma unroll
            for (int r = 0; r < 4; ++r) {
                const int gm = m0 + wm + f * 16 + hi * 4 + r;
                const int gn = n0 + wn + gq * 16 + lr;
                float v = acc[f][gq][r];
                if constexpr (EPI == 0) {
                    ((float*)Cp)[czoff + (long)gm * N + gn] = v;
                } else if constexpr (EPI == 1) {
                    v += bias[gn];
                    const float ge = 0.5f * v * (1.0f + erff(v * 0.70710678118f));
                    ((unsigned short*)Cp)[(long)gm * N + gn] = f2bf(ge);
                } else if constexpr (EPI == 2) {
                    float* c = (float*)Cp + (long)gm * N + gn;
                    *c = *c + v + bias[gn];
                } else if constexpr (EPI == 3) {
                    float* c = (float*)Cp + czoff + (long)gm * N + gn;
                    *c = *c + alpha * v;
                } else if constexpr (EPI == 4) {
                    const int tt = gm & (T_TOK - 1);
                    if (tt >= T2_TOK) {
                        const int bb = gm >> 10;
                        ((float*)Cp)[(long)(bb * T1_TOK + (tt - T2_TOK)) * VCLS + gn]
                            = v + bias[gn];
                    }
                } else { // EPI == 5: plain bf16 store
                    ((unsigned short*)Cp)[(long)gm * N + gn] = f2bf(v);
                }
            }
        }
    }
}

// ---------------------------------------------------------------------------
extern "C" void kernel_launch(void* const* d_in, const int* in_sizes, int n_in,
                              void* d_out, int out_size, void* d_ws, size_t ws_size,
                              hipStream_t stream)
{
    (void)in_sizes; (void)n_in; (void)out_size; (void)ws_size;
    const int*   xt   = (const int*)d_in[0];
    const int*   zi   = (const int*)d_in[1];
    const float* pos  = (const float*)d_in[2];
    const float* temb = (const float*)d_in[3];
    const float* iemb = (const float*)d_in[4];
    const float* ln1g = (const float*)d_in[5];
    const float* ln1b = (const float*)d_in[6];
    const float* Wq   = (const float*)d_in[7];
    const float* Wk   = (const float*)d_in[8];
    const float* Wv   = (const float*)d_in[9];
    const float* ln2g = (const float*)d_in[10];
    const float* ln2b = (const float*)d_in[11];
    const float* W1   = (const float*)d_in[12];
    const float* b1   = (const float*)d_in[13];
    const float* W2   = (const float*)d_in[14];
    const float* b2   = (const float*)d_in[15];
    const float* roW  = (const float*)d_in[16];
    const float* rob  = (const float*)d_in[17];
    float* out = (float*)d_out;

    // workspace layout (byte offsets; total 98,566,144 B — r1 proved >=100.7MB ok)
    char* wsb = (char*)d_ws;
    float*          H    = (float*)(wsb + 0);               // 16 MB fp32
    unsigned short* LNb  = (unsigned short*)(wsb + 16777216); // 8 MB bf16 (Hbf at end)
    float*          S    = (float*)(wsb + 25165824);          // 16 MB fp32 scores
    unsigned short* Vtmp = (unsigned short*)(wsb + 25165824); // overlaps S (dead then)
    unsigned short* Qb   = (unsigned short*)(wsb + 41943040); // 8 MB
    unsigned short* Kb   = (unsigned short*)(wsb + 50331648); // 8 MB
    unsigned short* VT   = (unsigned short*)(wsb + 58720256); // 8 MB
    unsigned short* Pb   = (unsigned short*)(wsb + 67108864); // 8 MB
    unsigned short* Hid  = (unsigned short*)(wsb + 41943040); // 32 MB, overlaps Q..P
    unsigned short* WqT  = (unsigned short*)(wsb + 75497472); // 2 MB
    unsigned short* WkT  = (unsigned short*)(wsb + 77594624);
    unsigned short* WvT  = (unsigned short*)(wsb + 79691776);
    unsigned short* W1T  = (unsigned short*)(wsb + 81788928); // 8 MB (roWT at end)
    unsigned short* W2T  = (unsigned short*)(wsb + 90177536); // 8 MB
    unsigned short* roWT = W1T;
    unsigned short* Hbf  = LNb;

    const long TD = (long)T_TOK * D_EMB;
    const long TT = (long)T_TOK * T_TOK;

    embed_kernel<<<4096, 256, 0, stream>>>(xt, zi, pos, temb, iemb, H);

    for (int lyr = 0; lyr < NLAYER; ++lyr) {
        const long dd = (long)lyr * D_EMB * D_EMB;
        const long d1 = (long)lyr * D_EMB * HMLP;
        wconv_kernel<<<11264, 256, 0, stream>>>(
            Wq + dd, Wk + dd, Wv + dd, W1 + d1, W2 + d1,
            WqT, WkT, WvT, W1T, W2T);
        ln_kernel<<<4096, 256, 0, stream>>>(H, ln1g + lyr * D_EMB, ln1b + lyr * D_EMB, LNb);
        // Q,K,V projections (z selects weight & output; V -> Vtmp)
        gemm_bt<5><<<dim3(8, 32, 3), 256, 0, stream>>>(
            LNb, WqT, WkT, WvT, Qb, Kb, Vtmp, nullptr,
            4096, D_EMB, D_EMB, 0L, 0L, 0L, 1.f);
        vtrans_kernel<<<dim3(32, 32, 4), 256, 0, stream>>>(Vtmp, VT);
        // scores = Q @ K^T per batch (fp32 out, overwrites Vtmp region)
        gemm_bt<0><<<dim3(8, 8, 4), 256, 0, stream>>>(
            Qb, Kb, nullptr, nullptr, S, nullptr, nullptr, nullptr,
            T_TOK, T_TOK, D_EMB, TD, TD, TT, 1.f);
        softmax_kernel<<<4096, 256, 0, stream>>>(S, Pb);
        // H += (1 + 1/D) * P @ V
        gemm_bt<3><<<dim3(8, 8, 4), 256, 0, stream>>>(
            Pb, VT, nullptr, nullptr, H, nullptr, nullptr, nullptr,
            T_TOK, D_EMB, T_TOK, TT, TD, TD, 1.0f + 1.0f / (float)D_EMB);
        ln_kernel<<<4096, 256, 0, stream>>>(H, ln2g + lyr * D_EMB, ln2b + lyr * D_EMB, LNb);
        // hidden = gelu(LN @ W1 + b1) -> bf16
        gemm_bt<1><<<dim3(32, 32, 1), 256, 0, stream>>>(
            LNb, W1T, nullptr, nullptr, Hid, nullptr, nullptr, b1 + (long)lyr * HMLP,
            4096, HMLP, D_EMB, 0L, 0L, 0L, 1.f);
        // H += hidden @ W2 + b2
        gemm_bt<2><<<dim3(8, 32, 1), 256, 0, stream>>>(
            Hid, W2T, nullptr, nullptr, H, nullptr, nullptr, b2 + (long)lyr * D_EMB,
            4096, D_EMB, HMLP, 0L, 0L, 0L, 1.f);
    }
    // readout: out = (H @ ro_W + ro_b)[:, T2:, :]
    cvt_bf16_kernel<<<4096, 256, 0, stream>>>(H, Hbf);
    convT_kernel<<<dim3(16, 32), 256, 0, stream>>>(roW, roWT, D_EMB, VCLS);
    gemm_bt<4><<<dim3(4, 32, 1), 256, 0, stream>>>(
        Hbf, roWT, nullptr, nullptr, out, nullptr, nullptr, rob,
        4096, VCLS, D_EMB, 0L, 0L, 0L, 1.f);
}

// Round 3
// 3394.114 us; speedup vs baseline: 2.0043x; 1.0874x over previous
//
#include <hip/hip_runtime.h>
#include <hip/hip_bf16.h>
#include <math.h>

#define D_EMB  1024
#define T_TOK  1024
#define T1_TOK 768
#define T2_TOK 256
#define HMLP   4096
#define NLAYER 12
#define VCLS   512

typedef __attribute__((ext_vector_type(8))) short          short8; // 8 bf16
typedef __attribute__((ext_vector_type(4))) float          f32x4;
typedef __attribute__((ext_vector_type(4))) unsigned short us4;

__device__ __forceinline__ unsigned short f2bf(float f) {
    union { float f; unsigned int u; } c; c.f = f;
    unsigned int u = c.u;
    return (unsigned short)((u + 0x7FFFu + ((u >> 16) & 1u)) >> 16); // RNE
}

__device__ __forceinline__ void gld_lds16(const unsigned short* g, unsigned short* l) {
    __builtin_amdgcn_global_load_lds(
        (__attribute__((address_space(1))) void*)g,
        (__attribute__((address_space(3))) void*)l, 16, 0, 0);
}

// ---------------------------------------------------------------------------
__global__ __launch_bounds__(256)
void embed_kernel(const int* __restrict__ xt, const int* __restrict__ zi,
                  const float* __restrict__ pos, const float* __restrict__ temb,
                  const float* __restrict__ iemb, float* __restrict__ H)
{
    const long idx = (long)blockIdx.x * 256 + threadIdx.x;
    const long e   = idx * 4;
    const int  dd  = (int)(e & (D_EMB - 1));
    const long bt  = e >> 10;
    const int  t   = (int)(bt & (T_TOK - 1));
    const int  b   = (int)(bt >> 10);
    const float* src;
    if (t < T2_TOK) src = iemb + (long)zi[b * T2_TOK + t] * D_EMB + dd;
    else            src = temb + (long)xt[b * T1_TOK + (t - T2_TOK)] * D_EMB + dd;
    float4 sv = *(const float4*)src;
    float4 pv = *(const float4*)(pos + (long)t * D_EMB + dd);
    float4 o; o.x = sv.x + pv.x; o.y = sv.y + pv.y; o.z = sv.z + pv.z; o.w = sv.w + pv.w;
    *(float4*)(H + e) = o;
}

// ---------------------------------------------------------------------------
__global__ __launch_bounds__(256)
void ln_kernel(const float* __restrict__ X, const float* __restrict__ g,
               const float* __restrict__ b, unsigned short* __restrict__ Y)
{
    const long row = blockIdx.x;
    const int  tid = threadIdx.x;
    float4 v = *(const float4*)(X + row * D_EMB + tid * 4);
    float s = v.x + v.y + v.z + v.w;
    float q = v.x*v.x + v.y*v.y + v.z*v.z + v.w*v.w;
    #pragma unroll
    for (int o = 32; o >= 1; o >>= 1) { s += __shfl_down(s, o); q += __shfl_down(q, o); }
    __shared__ float rs[4], rq[4];
    const int w = tid >> 6;
    if ((tid & 63) == 0) { rs[w] = s; rq[w] = q; }
    __syncthreads();
    s = rs[0] + rs[1] + rs[2] + rs[3];
    q = rq[0] + rq[1] + rq[2] + rq[3];
    const float mean = s * (1.0f / D_EMB);
    const float var  = q * (1.0f / D_EMB) - mean * mean;
    const float rstd = rsqrtf(var + 1e-5f);
    float4 gg = *(const float4*)(g + tid * 4);
    float4 bb = *(const float4*)(b + tid * 4);
    us4 o;
    o.x = f2bf((v.x - mean) * rstd * gg.x + bb.x);
    o.y = f2bf((v.y - mean) * rstd * gg.y + bb.y);
    o.z = f2bf((v.z - mean) * rstd * gg.z + bb.z);
    o.w = f2bf((v.w - mean) * rstd * gg.w + bb.w);
    *(us4*)(Y + row * D_EMB + tid * 4) = o;
}

// ---------------------------------------------------------------------------
__global__ __launch_bounds__(256)
void softmax_kernel(const float* __restrict__ S, unsigned short* __restrict__ P)
{
    const long row = blockIdx.x;
    const int  tid = threadIdx.x;
    float4 v = *(const float4*)(S + row * T_TOK + tid * 4);
    const float sc = 0.03125f; // 1/sqrt(1024)
    float a = v.x * sc, b = v.y * sc, c = v.z * sc, d = v.w * sc;
    float mx = fmaxf(fmaxf(a, b), fmaxf(c, d));
    #pragma unroll
    for (int o = 32; o >= 1; o >>= 1) mx = fmaxf(mx, __shfl_down(mx, o));
    __shared__ float rm[4], rsum[4];
    const int w = tid >> 6;
    if ((tid & 63) == 0) rm[w] = mx;
    __syncthreads();
    mx = fmaxf(fmaxf(rm[0], rm[1]), fmaxf(rm[2], rm[3]));
    float e0 = expf(a - mx), e1 = expf(b - mx), e2 = expf(c - mx), e3 = expf(d - mx);
    float s = e0 + e1 + e2 + e3;
    #pragma unroll
    for (int o = 32; o >= 1; o >>= 1) s += __shfl_down(s, o);
    if ((tid & 63) == 0) rsum[w] = s;
    __syncthreads();
    s = rsum[0] + rsum[1] + rsum[2] + rsum[3];
    const float inv = 1.0f / s;
    us4 o4; o4.x = f2bf(e0 * inv); o4.y = f2bf(e1 * inv);
    o4.z = f2bf(e2 * inv); o4.w = f2bf(e3 * inv);
    *(us4*)(P + row * T_TOK + tid * 4) = o4;
}

// ---------------------------------------------------------------------------
__global__ __launch_bounds__(256)
void convT_kernel(const float* __restrict__ src, unsigned short* __restrict__ dst,
                  int K, int N)
{
    __shared__ unsigned short tile[32][33];
    const int tn = blockIdx.x, tk = blockIdx.y;
    const int tx = threadIdx.x & 31, ty = threadIdx.x >> 5;
    #pragma unroll
    for (int i = 0; i < 4; ++i) {
        const int r = ty + i * 8;
        tile[r][tx] = f2bf(src[(long)(tk * 32 + r) * N + tn * 32 + tx]);
    }
    __syncthreads();
    #pragma unroll
    for (int i = 0; i < 4; ++i) {
        const int r = ty + i * 8;
        dst[(long)(tn * 32 + r) * K + tk * 32 + tx] = tile[tx][r];
    }
}

__global__ __launch_bounds__(256)
void wconv_kernel(const float* __restrict__ Wq, const float* __restrict__ Wk,
                  const float* __restrict__ Wv, const float* __restrict__ W1,
                  const float* __restrict__ W2,
                  unsigned short* __restrict__ WqT, unsigned short* __restrict__ WkT,
                  unsigned short* __restrict__ WvT, unsigned short* __restrict__ W1T,
                  unsigned short* __restrict__ W2T)
{
    __shared__ unsigned short tile[32][33];
    const int t = blockIdx.x;
    const float* src; unsigned short* dst; int K, N, tk, tn;
    if (t < 3072) {
        const int wsel = t >> 10, tt = t & 1023;
        src = (wsel == 0) ? Wq : (wsel == 1) ? Wk : Wv;
        dst = (wsel == 0) ? WqT : (wsel == 1) ? WkT : WvT;
        K = 1024; N = 1024; tn = tt & 31; tk = tt >> 5;
    } else if (t < 7168) {
        const int tt = t - 3072;
        src = W1; dst = W1T; K = 1024; N = 4096; tn = tt & 127; tk = tt >> 7;
    } else {
        const int tt = t - 7168;
        src = W2; dst = W2T; K = 4096; N = 1024; tn = tt & 31; tk = tt >> 5;
    }
    const int tx = threadIdx.x & 31, ty = threadIdx.x >> 5;
    #pragma unroll
    for (int i = 0; i < 4; ++i) {
        const int r = ty + i * 8;
        tile[r][tx] = f2bf(src[(long)(tk * 32 + r) * N + tn * 32 + tx]);
    }
    __syncthreads();
    #pragma unroll
    for (int i = 0; i < 4; ++i) {
        const int r = ty + i * 8;
        dst[(long)(tn * 32 + r) * K + tk * 32 + tx] = tile[tx][r];
    }
}

__global__ __launch_bounds__(256)
void vtrans_kernel(const unsigned short* __restrict__ src, unsigned short* __restrict__ dst)
{
    __shared__ unsigned short tile[32][33];
    const long so = (long)blockIdx.z * T_TOK * D_EMB;
    const int tn = blockIdx.x, tk = blockIdx.y;
    const int tx = threadIdx.x & 31, ty = threadIdx.x >> 5;
    #pragma unroll
    for (int i = 0; i < 4; ++i) {
        const int r = ty + i * 8;
        tile[r][tx] = src[so + (long)(tk * 32 + r) * D_EMB + tn * 32 + tx];
    }
    __syncthreads();
    #pragma unroll
    for (int i = 0; i < 4; ++i) {
        const int r = ty + i * 8;
        dst[so + (long)(tn * 32 + r) * T_TOK + tk * 32 + tx] = tile[tx][r];
    }
}

__global__ __launch_bounds__(256)
void cvt_bf16_kernel(const float* __restrict__ X, unsigned short* __restrict__ Y)
{
    const long i = ((long)blockIdx.x * 256 + threadIdx.x) * 4;
    float4 v = *(const float4*)(X + i);
    us4 o; o.x = f2bf(v.x); o.y = f2bf(v.y); o.z = f2bf(v.z); o.w = f2bf(v.w);
    *(us4*)(Y + i) = o;
}

// ---------------------------------------------------------------------------
// bf16 GEMM: C = epi(A @ B^T). A [M][K] bf16, B [N][K] bf16.
// Tile 128 x TN (TN in {64,128}), BK=32, 4 waves (2x2). global_load_lds 16B
// staging with k-slot XOR swizzle on BOTH global source and ds_read.
// XCD-aware bijective block swizzle, decoded n-major (blocks sharing a B/
// weight panel land contiguously on one XCD's L2).
// kLen < K => split-K across blockIdx.z (EPI must be atomic).
// EPI: 0 fp32 | 1 bias+gelu->bf16 | 2 C+=v+bias | 3 C+=alpha*v |
//      4 readout slice | 5 bf16 | 6 atomicAdd(v + bias@z0)
// ---------------------------------------------------------------------------
template<int EPI, int TN>
__global__ __launch_bounds__(256)
void gemm_bt(const unsigned short* __restrict__ A,
             const unsigned short* __restrict__ B0,
             const unsigned short* __restrict__ B1,
             const unsigned short* __restrict__ B2,
             void* __restrict__ C0, void* __restrict__ C1, void* __restrict__ C2,
             const float* __restrict__ bias,
             int M, int N, int K, int kLen,
             long sAz, long sBz, long sCz, float alpha)
{
    constexpr int FN = TN / 32;          // B frags per wave
    __shared__ unsigned short As[128 * 32];
    __shared__ unsigned short Bs[TN * 32];

    const int z = blockIdx.z;
    const unsigned short* Ap = A + (long)z * sAz;
    const unsigned short* Bp = (B1 != nullptr) ? (z == 0 ? B0 : (z == 1 ? B1 : B2))
                                               : B0 + (long)z * sBz;
    void* Cp = (C1 != nullptr) ? (z == 0 ? C0 : (z == 1 ? C1 : C2)) : C0;
    const long czoff = (C1 != nullptr) ? 0 : (long)z * sCz;

    // XCD swizzle (per-z slice; gx*gy % 8 == 0 for all our launches)
    const int gx = gridDim.x, gy = gridDim.y;
    const int o  = blockIdx.x + gx * blockIdx.y;
    const int nwg = gx * gy;
    const int virt = (nwg & 7) ? o : ((o & 7) * (nwg >> 3) + (o >> 3));
    const int ntile = virt / gy;
    const int mtile = virt - ntile * gy;
    const int m0 = mtile * 128, n0 = ntile * TN;
    const int kOff = (kLen < K) ? z * kLen : 0;

    const int tid = threadIdx.x;
    const int l = tid & 63, w = tid >> 6;
    const int wm = (w >> 1) * 64, wn = (w & 1) * (TN / 2);
    const int lr = l & 15, hi = l >> 4;

    // staging: 4 lanes/row (16B each), swizzled global k-slot
    const int r0 = tid >> 2;                    // 0..63
    const int s0 = (tid & 3) ^ ((r0 >> 1) & 3); // row+64 gives same swz bits
    const unsigned short* gA0 = Ap + (long)(m0 + r0) * K + kOff + s0 * 8;
    const unsigned short* gA1 = Ap + (long)(m0 + r0 + 64) * K + kOff + s0 * 8;
    const unsigned short* gB0 = Bp + (long)(n0 + r0) * K + kOff + s0 * 8;
    const unsigned short* gB1 = (TN == 128) ? Bp + (long)(n0 + r0 + 64) * K + kOff + s0 * 8
                                            : nullptr;
    unsigned short* lA0 = As + (w * 64) * 8;
    unsigned short* lA1 = As + (256 + w * 64) * 8;
    unsigned short* lB0 = Bs + (w * 64) * 8;
    unsigned short* lB1 = Bs + (256 + w * 64) * 8;

    f32x4 acc[4][FN];
    #pragma unroll
    for (int f = 0; f < 4; ++f)
        #pragma unroll
        for (int gq = 0; gq < FN; ++gq)
            acc[f][gq] = (f32x4){0.f, 0.f, 0.f, 0.f};

    for (int k0 = 0; k0 < kLen; k0 += 32) {
        gld_lds16(gA0 + k0, lA0);
        gld_lds16(gA1 + k0, lA1);
        gld_lds16(gB0 + k0, lB0);
        if constexpr (TN == 128) gld_lds16(gB1 + k0, lB1);
        __syncthreads();
        short8 af[4], bg[FN];
        #pragma unroll
        for (int f = 0; f < 4; ++f) {
            const int rr = wm + f * 16 + lr;
            const int sl = hi ^ ((rr >> 1) & 3);
            af[f] = *(const short8*)&As[rr * 32 + sl * 8];
        }
        #pragma unroll
        for (int gq = 0; gq < FN; ++gq) {
            const int rn = wn + gq * 16 + lr;
            const int sl = hi ^ ((rn >> 1) & 3);
            bg[gq] = *(const short8*)&Bs[rn * 32 + sl * 8];
        }
        #pragma unroll
        for (int f = 0; f < 4; ++f)
            #pragma unroll
            for (int gq = 0; gq < FN; ++gq)
                acc[f][gq] = __builtin_amdgcn_mfma_f32_16x16x32_bf16(
                    af[f], bg[gq], acc[f][gq], 0, 0, 0);
        __syncthreads();
    }

    // D mapping: col = lane&15, row = (lane>>4)*4 + r
    #pragma unroll
    for (int f = 0; f < 4; ++f) {
        #pragma unroll
        for (int gq = 0; gq < FN; ++gq) {
            #pragma unroll
            for (int r = 0; r < 4; ++r) {
                const int gm = m0 + wm + f * 16 + hi * 4 + r;
                const int gn = n0 + wn + gq * 16 + lr;
                float v = acc[f][gq][r];
                if constexpr (EPI == 0) {
                    ((float*)Cp)[czoff + (long)gm * N + gn] = v;
                } else if constexpr (EPI == 1) {
                    v += bias[gn];
                    const float ge = 0.5f * v * (1.0f + erff(v * 0.70710678118f));
                    ((unsigned short*)Cp)[(long)gm * N + gn] = f2bf(ge);
                } else if constexpr (EPI == 2) {
                    float* c = (float*)Cp + (long)gm * N + gn;
                    *c = *c + v + bias[gn];
                } else if constexpr (EPI == 3) {
                    float* c = (float*)Cp + czoff + (long)gm * N + gn;
                    *c = *c + alpha * v;
                } else if constexpr (EPI == 4) {
                    const int tt = gm & (T_TOK - 1);
                    if (tt >= T2_TOK) {
                        const int bb = gm >> 10;
                        ((float*)Cp)[(long)(bb * T1_TOK + (tt - T2_TOK)) * VCLS + gn]
                            = v + bias[gn];
                    }
                } else if constexpr (EPI == 5) {
                    ((unsigned short*)Cp)[(long)gm * N + gn] = f2bf(v);
                } else { // EPI == 6: split-K accumulate into C
                    atomicAdd((float*)Cp + (long)gm * N + gn,
                              v + ((z == 0) ? bias[gn] : 0.f));
                }
            }
        }
    }
}

// ---------------------------------------------------------------------------
extern "C" void kernel_launch(void* const* d_in, const int* in_sizes, int n_in,
                              void* d_out, int out_size, void* d_ws, size_t ws_size,
                              hipStream_t stream)
{
    (void)in_sizes; (void)n_in; (void)out_size; (void)ws_size;
    const int*   xt   = (const int*)d_in[0];
    const int*   zi   = (const int*)d_in[1];
    const float* pos  = (const float*)d_in[2];
    const float* temb = (const float*)d_in[3];
    const float* iemb = (const float*)d_in[4];
    const float* ln1g = (const float*)d_in[5];
    const float* ln1b = (const float*)d_in[6];
    const float* Wq   = (const float*)d_in[7];
    const float* Wk   = (const float*)d_in[8];
    const float* Wv   = (const float*)d_in[9];
    const float* ln2g = (const float*)d_in[10];
    const float* ln2b = (const float*)d_in[11];
    const float* W1   = (const float*)d_in[12];
    const float* b1   = (const float*)d_in[13];
    const float* W2   = (const float*)d_in[14];
    const float* b2   = (const float*)d_in[15];
    const float* roW  = (const float*)d_in[16];
    const float* rob  = (const float*)d_in[17];
    float* out = (float*)d_out;

    char* wsb = (char*)d_ws;
    float*          H    = (float*)(wsb + 0);                 // 16 MB fp32
    unsigned short* LNb  = (unsigned short*)(wsb + 16777216); // 8 MB bf16
    float*          S    = (float*)(wsb + 25165824);          // 16 MB fp32
    unsigned short* Vtmp = (unsigned short*)(wsb + 25165824); // overlaps S
    unsigned short* Qb   = (unsigned short*)(wsb + 41943040); // 8 MB
    unsigned short* Kb   = (unsigned short*)(wsb + 50331648); // 8 MB
    unsigned short* VT   = (unsigned short*)(wsb + 58720256); // 8 MB
    unsigned short* Pb   = (unsigned short*)(wsb + 67108864); // 8 MB
    unsigned short* Hid  = (unsigned short*)(wsb + 41943040); // 32 MB, overlaps Q..P
    unsigned short* WqT  = (unsigned short*)(wsb + 75497472); // 2 MB
    unsigned short* WkT  = (unsigned short*)(wsb + 77594624);
    unsigned short* WvT  = (unsigned short*)(wsb + 79691776);
    unsigned short* W1T  = (unsigned short*)(wsb + 81788928); // 8 MB
    unsigned short* W2T  = (unsigned short*)(wsb + 90177536); // 8 MB
    unsigned short* roWT = W1T;
    unsigned short* Hbf  = LNb;

    const long TD = (long)T_TOK * D_EMB;
    const long TT = (long)T_TOK * T_TOK;

    embed_kernel<<<4096, 256, 0, stream>>>(xt, zi, pos, temb, iemb, H);

    for (int lyr = 0; lyr < NLAYER; ++lyr) {
        const long dd = (long)lyr * D_EMB * D_EMB;
        const long d1 = (long)lyr * D_EMB * HMLP;
        wconv_kernel<<<11264, 256, 0, stream>>>(
            Wq + dd, Wk + dd, Wv + dd, W1 + d1, W2 + d1,
            WqT, WkT, WvT, W1T, W2T);
        ln_kernel<<<4096, 256, 0, stream>>>(H, ln1g + lyr * D_EMB, ln1b + lyr * D_EMB, LNb);
        // Q,K,V projections (z selects weight & output)
        gemm_bt<5, 128><<<dim3(8, 32, 3), 256, 0, stream>>>(
            LNb, WqT, WkT, WvT, Qb, Kb, Vtmp, nullptr,
            4096, D_EMB, D_EMB, D_EMB, 0L, 0L, 0L, 1.f);
        vtrans_kernel<<<dim3(32, 32, 4), 256, 0, stream>>>(Vtmp, VT);
        // scores = Q @ K^T per batch
        gemm_bt<0, 64><<<dim3(16, 8, 4), 256, 0, stream>>>(
            Qb, Kb, nullptr, nullptr, S, nullptr, nullptr, nullptr,
            T_TOK, T_TOK, D_EMB, D_EMB, TD, TD, TT, 1.f);
        softmax_kernel<<<4096, 256, 0, stream>>>(S, Pb);
        // H += (1 + 1/D) * P @ V
        gemm_bt<3, 64><<<dim3(16, 8, 4), 256, 0, stream>>>(
            Pb, VT, nullptr, nullptr, H, nullptr, nullptr, nullptr,
            T_TOK, D_EMB, T_TOK, T_TOK, TT, TD, TD, 1.0f + 1.0f / (float)D_EMB);
        ln_kernel<<<4096, 256, 0, stream>>>(H, ln2g + lyr * D_EMB, ln2b + lyr * D_EMB, LNb);
        // hidden = gelu(LN @ W1 + b1) -> bf16
        gemm_bt<1, 128><<<dim3(32, 32, 1), 256, 0, stream>>>(
            LNb, W1T, nullptr, nullptr, Hid, nullptr, nullptr, b1 + (long)lyr * HMLP,
            4096, HMLP, D_EMB, D_EMB, 0L, 0L, 0L, 1.f);
        // H += hidden @ W2 + b2  (split-K x2, atomic accumulate)
        gemm_bt<6, 128><<<dim3(8, 32, 2), 256, 0, stream>>>(
            Hid, W2T, nullptr, nullptr, H, nullptr, nullptr, b2 + (long)lyr * D_EMB,
            4096, D_EMB, HMLP, HMLP / 2, 0L, 0L, 0L, 1.f);
    }
    // readout: out = (H @ ro_W + ro_b)[:, T2:, :]
    cvt_bf16_kernel<<<4096, 256, 0, stream>>>(H, Hbf);
    convT_kernel<<<dim3(16, 32), 256, 0, stream>>>(roW, roWT, D_EMB, VCLS);
    gemm_bt<4, 64><<<dim3(8, 32, 1), 256, 0, stream>>>(
        Hbf, roWT, nullptr, nullptr, out, nullptr, nullptr, rob,
        4096, VCLS, D_EMB, D_EMB, 0L, 0L, 0L, 1.f);
}

// Round 4
// 3110.693 us; speedup vs baseline: 2.1870x; 1.0911x over previous
//
#include <hip/hip_runtime.h>
#include <hip/hip_bf16.h>
#include <math.h>

#define D_EMB  1024
#define T_TOK  1024
#define T1_TOK 768
#define T2_TOK 256
#define HMLP   4096
#define NLAYER 12
#define VCLS   512

typedef __attribute__((ext_vector_type(8))) short          short8; // 8 bf16
typedef __attribute__((ext_vector_type(4))) float          f32x4;
typedef __attribute__((ext_vector_type(4))) unsigned short us4;

__device__ __forceinline__ unsigned short f2bf(float f) {
    union { float f; unsigned int u; } c; c.f = f;
    unsigned int u = c.u;
    return (unsigned short)((u + 0x7FFFu + ((u >> 16) & 1u)) >> 16); // RNE
}

__device__ __forceinline__ void gld_lds16(const unsigned short* g, unsigned short* l) {
    __builtin_amdgcn_global_load_lds(
        (__attribute__((address_space(1))) void*)g,
        (__attribute__((address_space(3))) void*)l, 16, 0, 0);
}

// ---------------------------------------------------------------------------
__global__ __launch_bounds__(256)
void embed_kernel(const int* __restrict__ xt, const int* __restrict__ zi,
                  const float* __restrict__ pos, const float* __restrict__ temb,
                  const float* __restrict__ iemb, float* __restrict__ H)
{
    const long idx = (long)blockIdx.x * 256 + threadIdx.x;
    const long e   = idx * 4;
    const int  dd  = (int)(e & (D_EMB - 1));
    const long bt  = e >> 10;
    const int  t   = (int)(bt & (T_TOK - 1));
    const int  b   = (int)(bt >> 10);
    const float* src;
    if (t < T2_TOK) src = iemb + (long)zi[b * T2_TOK + t] * D_EMB + dd;
    else            src = temb + (long)xt[b * T1_TOK + (t - T2_TOK)] * D_EMB + dd;
    float4 sv = *(const float4*)src;
    float4 pv = *(const float4*)(pos + (long)t * D_EMB + dd);
    float4 o; o.x = sv.x + pv.x; o.y = sv.y + pv.y; o.z = sv.z + pv.z; o.w = sv.w + pv.w;
    *(float4*)(H + e) = o;
}

// ---------------------------------------------------------------------------
__global__ __launch_bounds__(256)
void ln_kernel(const float* __restrict__ X, const float* __restrict__ g,
               const float* __restrict__ b, unsigned short* __restrict__ Y)
{
    const long row = blockIdx.x;
    const int  tid = threadIdx.x;
    float4 v = *(const float4*)(X + row * D_EMB + tid * 4);
    float s = v.x + v.y + v.z + v.w;
    float q = v.x*v.x + v.y*v.y + v.z*v.z + v.w*v.w;
    #pragma unroll
    for (int o = 32; o >= 1; o >>= 1) { s += __shfl_down(s, o); q += __shfl_down(q, o); }
    __shared__ float rs[4], rq[4];
    const int w = tid >> 6;
    if ((tid & 63) == 0) { rs[w] = s; rq[w] = q; }
    __syncthreads();
    s = rs[0] + rs[1] + rs[2] + rs[3];
    q = rq[0] + rq[1] + rq[2] + rq[3];
    const float mean = s * (1.0f / D_EMB);
    const float var  = q * (1.0f / D_EMB) - mean * mean;
    const float rstd = rsqrtf(var + 1e-5f);
    float4 gg = *(const float4*)(g + tid * 4);
    float4 bb = *(const float4*)(b + tid * 4);
    us4 o;
    o.x = f2bf((v.x - mean) * rstd * gg.x + bb.x);
    o.y = f2bf((v.y - mean) * rstd * gg.y + bb.y);
    o.z = f2bf((v.z - mean) * rstd * gg.z + bb.z);
    o.w = f2bf((v.w - mean) * rstd * gg.w + bb.w);
    *(us4*)(Y + row * D_EMB + tid * 4) = o;
}

// ---------------------------------------------------------------------------
__global__ __launch_bounds__(256)
void softmax_kernel(const float* __restrict__ S, unsigned short* __restrict__ P)
{
    const long row = blockIdx.x;
    const int  tid = threadIdx.x;
    float4 v = *(const float4*)(S + row * T_TOK + tid * 4);
    const float sc = 0.03125f; // 1/sqrt(1024)
    float a = v.x * sc, b = v.y * sc, c = v.z * sc, d = v.w * sc;
    float mx = fmaxf(fmaxf(a, b), fmaxf(c, d));
    #pragma unroll
    for (int o = 32; o >= 1; o >>= 1) mx = fmaxf(mx, __shfl_down(mx, o));
    __shared__ float rm[4], rsum[4];
    const int w = tid >> 6;
    if ((tid & 63) == 0) rm[w] = mx;
    __syncthreads();
    mx = fmaxf(fmaxf(rm[0], rm[1]), fmaxf(rm[2], rm[3]));
    float e0 = expf(a - mx), e1 = expf(b - mx), e2 = expf(c - mx), e3 = expf(d - mx);
    float s = e0 + e1 + e2 + e3;
    #pragma unroll
    for (int o = 32; o >= 1; o >>= 1) s += __shfl_down(s, o);
    if ((tid & 63) == 0) rsum[w] = s;
    __syncthreads();
    s = rsum[0] + rsum[1] + rsum[2] + rsum[3];
    const float inv = 1.0f / s;
    us4 o4; o4.x = f2bf(e0 * inv); o4.y = f2bf(e1 * inv);
    o4.z = f2bf(e2 * inv); o4.w = f2bf(e3 * inv);
    *(us4*)(P + row * T_TOK + tid * 4) = o4;
}

// ---------------------------------------------------------------------------
__global__ __launch_bounds__(256)
void convT_kernel(const float* __restrict__ src, unsigned short* __restrict__ dst,
                  int K, int N)
{
    __shared__ unsigned short tile[32][33];
    const int tn = blockIdx.x, tk = blockIdx.y;
    const int tx = threadIdx.x & 31, ty = threadIdx.x >> 5;
    #pragma unroll
    for (int i = 0; i < 4; ++i) {
        const int r = ty + i * 8;
        tile[r][tx] = f2bf(src[(long)(tk * 32 + r) * N + tn * 32 + tx]);
    }
    __syncthreads();
    #pragma unroll
    for (int i = 0; i < 4; ++i) {
        const int r = ty + i * 8;
        dst[(long)(tn * 32 + r) * K + tk * 32 + tx] = tile[tx][r];
    }
}

__global__ __launch_bounds__(256)
void wconv_kernel(const float* __restrict__ Wq, const float* __restrict__ Wk,
                  const float* __restrict__ Wv, const float* __restrict__ W1,
                  const float* __restrict__ W2,
                  unsigned short* __restrict__ WqT, unsigned short* __restrict__ WkT,
                  unsigned short* __restrict__ WvT, unsigned short* __restrict__ W1T,
                  unsigned short* __restrict__ W2T)
{
    __shared__ unsigned short tile[32][33];
    const int t = blockIdx.x;
    const float* src; unsigned short* dst; int K, N, tk, tn;
    if (t < 3072) {
        const int wsel = t >> 10, tt = t & 1023;
        src = (wsel == 0) ? Wq : (wsel == 1) ? Wk : Wv;
        dst = (wsel == 0) ? WqT : (wsel == 1) ? WkT : WvT;
        K = 1024; N = 1024; tn = tt & 31; tk = tt >> 5;
    } else if (t < 7168) {
        const int tt = t - 3072;
        src = W1; dst = W1T; K = 1024; N = 4096; tn = tt & 127; tk = tt >> 7;
    } else {
        const int tt = t - 7168;
        src = W2; dst = W2T; K = 4096; N = 1024; tn = tt & 31; tk = tt >> 5;
    }
    const int tx = threadIdx.x & 31, ty = threadIdx.x >> 5;
    #pragma unroll
    for (int i = 0; i < 4; ++i) {
        const int r = ty + i * 8;
        tile[r][tx] = f2bf(src[(long)(tk * 32 + r) * N + tn * 32 + tx]);
    }
    __syncthreads();
    #pragma unroll
    for (int i = 0; i < 4; ++i) {
        const int r = ty + i * 8;
        dst[(long)(tn * 32 + r) * K + tk * 32 + tx] = tile[tx][r];
    }
}

__global__ __launch_bounds__(256)
void cvt_bf16_kernel(const float* __restrict__ X, unsigned short* __restrict__ Y)
{
    const long i = ((long)blockIdx.x * 256 + threadIdx.x) * 4;
    float4 v = *(const float4*)(X + i);
    us4 o; o.x = f2bf(v.x); o.y = f2bf(v.y); o.z = f2bf(v.z); o.w = f2bf(v.w);
    *(us4*)(Y + i) = o;
}

// ---------------------------------------------------------------------------
// bf16 GEMM, 2-phase double-buffered (T3 minimum recipe):
//   STAGE(t+1 -> buf^1) issued FIRST, then ds_read+MFMA on buf, then ONE
//   __syncthreads() (drains vmcnt+lgkm) per K-step. Next-tile load latency
//   hides under current-tile compute.
// C = epi(A @ B^T). A [M][K] bf16, B [N][K] bf16. Tile 128 x TN, BK=32,
// 4 waves (2x2). global_load_lds 16B staging, k-slot XOR swizzle on both
// global source and ds_read. XCD-aware bijective block swizzle (n-major).
// kLen < K => split-K across z.
// EPI: 0 fp32 | 1 bias+gelu->bf16 | 3 C+=alpha*v | 4 readout (24-tile remap)
//      | 5 bf16 | 6 atomicAdd(v+bias@z0) | 7 QKV combo (bf16; z==2 -> V^T)
// ---------------------------------------------------------------------------
template<int EPI, int TN>
__global__ __launch_bounds__(256)
void gemm_bt(const unsigned short* __restrict__ A,
             const unsigned short* __restrict__ B0,
             const unsigned short* __restrict__ B1,
             const unsigned short* __restrict__ B2,
             void* __restrict__ C0, void* __restrict__ C1, void* __restrict__ C2,
             const float* __restrict__ bias,
             int M, int N, int K, int kLen,
             long sAz, long sBz, long sCz, float alpha)
{
    constexpr int FN = TN / 32;          // B frags per wave
    constexpr int ABUF = 128 * 32;       // us per A buffer
    constexpr int BBUF = TN * 32;
    __shared__ unsigned short As[2 * ABUF];
    __shared__ unsigned short Bs[2 * BBUF];

    const int z = blockIdx.z;
    const unsigned short* Ap = A + (long)z * sAz;
    const unsigned short* Bp = (B1 != nullptr) ? (z == 0 ? B0 : (z == 1 ? B1 : B2))
                                               : B0 + (long)z * sBz;
    void* Cp = (C1 != nullptr) ? (z == 0 ? C0 : (z == 1 ? C1 : C2)) : C0;
    const long czoff = (C1 != nullptr) ? 0 : (long)z * sCz;

    // XCD swizzle (bijective: all launches have gx*gy % 8 == 0)
    const int gx = gridDim.x, gy = gridDim.y;
    const int o  = blockIdx.x + gx * blockIdx.y;
    const int nwg = gx * gy;
    const int virt = (nwg & 7) ? o : ((o & 7) * (nwg >> 3) + (o >> 3));
    const int ntile = virt / gy;
    int mtile = virt - ntile * gy;
    if constexpr (EPI == 4) mtile = (mtile / 6) * 8 + 2 + (mtile % 6); // skip t<T2 tiles
    const int m0 = mtile * 128, n0 = ntile * TN;
    const int kOff = (kLen < K) ? z * kLen : 0;

    const int tid = threadIdx.x;
    const int l = tid & 63, w = tid >> 6;
    const int wm = (w >> 1) * 64, wn = (w & 1) * (TN / 2);
    const int lr = l & 15, hi = l >> 4;

    // staging: 4 lanes/row (16B each), swizzled global k-slot
    const int r0 = tid >> 2;                    // 0..63
    const int s0 = (tid & 3) ^ ((r0 >> 1) & 3);
    const unsigned short* gA0 = Ap + (long)(m0 + r0) * K + kOff + s0 * 8;
    const unsigned short* gA1 = Ap + (long)(m0 + r0 + 64) * K + kOff + s0 * 8;
    const unsigned short* gB0 = Bp + (long)(n0 + r0) * K + kOff + s0 * 8;
    const unsigned short* gB1 = (TN == 128) ? Bp + (long)(n0 + r0 + 64) * K + kOff + s0 * 8
                                            : nullptr;
    const int lA0 = w * 512, lA1 = 2048 + w * 512;   // us offsets within a buffer
    const int lB0 = w * 512, lB1 = 2048 + w * 512;

    f32x4 acc[4][FN];
    #pragma unroll
    for (int f = 0; f < 4; ++f)
        #pragma unroll
        for (int gq = 0; gq < FN; ++gq)
            acc[f][gq] = (f32x4){0.f, 0.f, 0.f, 0.f};

    const int nk = kLen >> 5;
    // prologue: stage tile 0 into buf 0
    gld_lds16(gA0, As + lA0);
    gld_lds16(gA1, As + lA1);
    gld_lds16(gB0, Bs + lB0);
    if constexpr (TN == 128) gld_lds16(gB1, Bs + lB1);
    __syncthreads();

    for (int t = 0; t < nk; ++t) {
        const int cur = t & 1;
        const int aB = (cur ^ 1) * ABUF, bB = (cur ^ 1) * BBUF;
        if (t + 1 < nk) {               // issue next-tile stage FIRST
            const int k1 = (t + 1) << 5;
            gld_lds16(gA0 + k1, As + aB + lA0);
            gld_lds16(gA1 + k1, As + aB + lA1);
            gld_lds16(gB0 + k1, Bs + bB + lB0);
            if constexpr (TN == 128) gld_lds16(gB1 + k1, Bs + bB + lB1);
        }
        const int aC = cur * ABUF, bC = cur * BBUF;
        short8 af[4], bg[FN];
        #pragma unroll
        for (int f = 0; f < 4; ++f) {
            const int rr = wm + f * 16 + lr;
            const int sl = hi ^ ((rr >> 1) & 3);
            af[f] = *(const short8*)&As[aC + rr * 32 + sl * 8];
        }
        #pragma unroll
        for (int gq = 0; gq < FN; ++gq) {
            const int rn = wn + gq * 16 + lr;
            const int sl = hi ^ ((rn >> 1) & 3);
            bg[gq] = *(const short8*)&Bs[bC + rn * 32 + sl * 8];
        }
        #pragma unroll
        for (int f = 0; f < 4; ++f)
            #pragma unroll
            for (int gq = 0; gq < FN; ++gq)
                acc[f][gq] = __builtin_amdgcn_mfma_f32_16x16x32_bf16(
                    af[f], bg[gq], acc[f][gq], 0, 0, 0);
        __syncthreads();   // drains STAGE(t+1) vmcnt; frees buf[cur] for t+2
    }

    // D mapping: col = lane&15, row = (lane>>4)*4 + r
    #pragma unroll
    for (int f = 0; f < 4; ++f) {
        #pragma unroll
        for (int gq = 0; gq < FN; ++gq) {
            const int gm0 = m0 + wm + f * 16 + hi * 4;
            const int gn  = n0 + wn + gq * 16 + lr;
            if constexpr (EPI == 7) {
                if (z == 2) { // V^T: VT[b][d=gn][t] , 4 consecutive t
                    us4 ov;
                    ov.x = f2bf(acc[f][gq][0]); ov.y = f2bf(acc[f][gq][1]);
                    ov.z = f2bf(acc[f][gq][2]); ov.w = f2bf(acc[f][gq][3]);
                    const long idx = (long)(gm0 >> 10) * (T_TOK * D_EMB)
                                   + (long)gn * T_TOK + (gm0 & (T_TOK - 1));
                    *(us4*)&((unsigned short*)Cp)[idx] = ov;
                    continue;
                }
            }
            #pragma unroll
            for (int r = 0; r < 4; ++r) {
                const int gm = gm0 + r;
                float v = acc[f][gq][r];
                if constexpr (EPI == 0) {
                    ((float*)Cp)[czoff + (long)gm * N + gn] = v;
                } else if constexpr (EPI == 1) {
                    v += bias[gn];
                    const float ge = 0.5f * v * (1.0f + erff(v * 0.70710678118f));
                    ((unsigned short*)Cp)[(long)gm * N + gn] = f2bf(ge);
                } else if constexpr (EPI == 3) {
                    float* c = (float*)Cp + czoff + (long)gm * N + gn;
                    *c = *c + alpha * v;
                } else if constexpr (EPI == 4) {
                    const int tt = gm & (T_TOK - 1);
                    ((float*)Cp)[(long)((gm >> 10) * T1_TOK + (tt - T2_TOK)) * VCLS + gn]
                        = v + bias[gn];
                } else if constexpr (EPI == 5 || EPI == 7) {
                    ((unsigned short*)Cp)[(long)gm * N + gn] = f2bf(v);
                } else if constexpr (EPI == 6) {
                    atomicAdd((float*)Cp + (long)gm * N + gn,
                              v + ((z == 0) ? bias[gn] : 0.f));
                }
            }
        }
    }
}

// ---------------------------------------------------------------------------
extern "C" void kernel_launch(void* const* d_in, const int* in_sizes, int n_in,
                              void* d_out, int out_size, void* d_ws, size_t ws_size,
                              hipStream_t stream)
{
    (void)in_sizes; (void)n_in; (void)out_size; (void)ws_size;
    const int*   xt   = (const int*)d_in[0];
    const int*   zi   = (const int*)d_in[1];
    const float* pos  = (const float*)d_in[2];
    const float* temb = (const float*)d_in[3];
    const float* iemb = (const float*)d_in[4];
    const float* ln1g = (const float*)d_in[5];
    const float* ln1b = (const float*)d_in[6];
    const float* Wq   = (const float*)d_in[7];
    const float* Wk   = (const float*)d_in[8];
    const float* Wv   = (const float*)d_in[9];
    const float* ln2g = (const float*)d_in[10];
    const float* ln2b = (const float*)d_in[11];
    const float* W1   = (const float*)d_in[12];
    const float* b1   = (const float*)d_in[13];
    const float* W2   = (const float*)d_in[14];
    const float* b2   = (const float*)d_in[15];
    const float* roW  = (const float*)d_in[16];
    const float* rob  = (const float*)d_in[17];
    float* out = (float*)d_out;

    char* wsb = (char*)d_ws;
    float*          H    = (float*)(wsb + 0);                 // 16 MB fp32
    unsigned short* LNb  = (unsigned short*)(wsb + 16777216); // 8 MB bf16
    float*          S    = (float*)(wsb + 25165824);          // 16 MB fp32
    unsigned short* Qb   = (unsigned short*)(wsb + 41943040); // 8 MB
    unsigned short* Kb   = (unsigned short*)(wsb + 50331648); // 8 MB
    unsigned short* VT   = (unsigned short*)(wsb + 58720256); // 8 MB (V^T per batch)
    unsigned short* Pb   = (unsigned short*)(wsb + 67108864); // 8 MB
    unsigned short* Hid  = (unsigned short*)(wsb + 41943040); // 32 MB, overlaps Q..P
    unsigned short* WqT  = (unsigned short*)(wsb + 75497472); // 2 MB
    unsigned short* WkT  = (unsigned short*)(wsb + 77594624);
    unsigned short* WvT  = (unsigned short*)(wsb + 79691776);
    unsigned short* W1T  = (unsigned short*)(wsb + 81788928); // 8 MB
    unsigned short* W2T  = (unsigned short*)(wsb + 90177536); // 8 MB
    unsigned short* roWT = W1T;
    unsigned short* Hbf  = LNb;

    const long TD = (long)T_TOK * D_EMB;
    const long TT = (long)T_TOK * T_TOK;

    embed_kernel<<<4096, 256, 0, stream>>>(xt, zi, pos, temb, iemb, H);

    for (int lyr = 0; lyr < NLAYER; ++lyr) {
        const long dd = (long)lyr * D_EMB * D_EMB;
        const long d1 = (long)lyr * D_EMB * HMLP;
        wconv_kernel<<<11264, 256, 0, stream>>>(
            Wq + dd, Wk + dd, Wv + dd, W1 + d1, W2 + d1,
            WqT, WkT, WvT, W1T, W2T);
        ln_kernel<<<4096, 256, 0, stream>>>(H, ln1g + lyr * D_EMB, ln1b + lyr * D_EMB, LNb);
        // Q,K,V projections; z==2 writes V^T directly
        gemm_bt<7, 128><<<dim3(8, 32, 3), 256, 0, stream>>>(
            LNb, WqT, WkT, WvT, Qb, Kb, VT, nullptr,
            4096, D_EMB, D_EMB, D_EMB, 0L, 0L, 0L, 1.f);
        // scores = Q @ K^T per batch
        gemm_bt<0, 64><<<dim3(16, 8, 4), 256, 0, stream>>>(
            Qb, Kb, nullptr, nullptr, S, nullptr, nullptr, nullptr,
            T_TOK, T_TOK, D_EMB, D_EMB, TD, TD, TT, 1.f);
        softmax_kernel<<<4096, 256, 0, stream>>>(S, Pb);
        // H += (1 + 1/D) * P @ V
        gemm_bt<3, 64><<<dim3(16, 8, 4), 256, 0, stream>>>(
            Pb, VT, nullptr, nullptr, H, nullptr, nullptr, nullptr,
            T_TOK, D_EMB, T_TOK, T_TOK, TT, TD, TD, 1.0f + 1.0f / (float)D_EMB);
        ln_kernel<<<4096, 256, 0, stream>>>(H, ln2g + lyr * D_EMB, ln2b + lyr * D_EMB, LNb);
        // hidden = gelu(LN @ W1 + b1) -> bf16
        gemm_bt<1, 128><<<dim3(32, 32, 1), 256, 0, stream>>>(
            LNb, W1T, nullptr, nullptr, Hid, nullptr, nullptr, b1 + (long)lyr * HMLP,
            4096, HMLP, D_EMB, D_EMB, 0L, 0L, 0L, 1.f);
        // H += hidden @ W2 + b2  (split-K x2, atomic accumulate)
        gemm_bt<6, 128><<<dim3(8, 32, 2), 256, 0, stream>>>(
            Hid, W2T, nullptr, nullptr, H, nullptr, nullptr, b2 + (long)lyr * D_EMB,
            4096, D_EMB, HMLP, HMLP / 2, 0L, 0L, 0L, 1.f);
    }
    // readout: out = (H @ ro_W + ro_b)[:, T2:, :]  (only the 24 needed m-tiles)
    cvt_bf16_kernel<<<4096, 256, 0, stream>>>(H, Hbf);
    convT_kernel<<<dim3(16, 32), 256, 0, stream>>>(roW, roWT, D_EMB, VCLS);
    gemm_bt<4, 64><<<dim3(8, 24, 1), 256, 0, stream>>>(
        Hbf, roWT, nullptr, nullptr, out, nullptr, nullptr, rob,
        4096, VCLS, D_EMB, D_EMB, 0L, 0L, 0L, 1.f);
}